// Round 2
// baseline (208.779 us; speedup 1.0000x reference)
//
#include <hip/hip_runtime.h>

// PopulationCoding fused kernel, round 2:
//   - TK=32 double-buffered LDS (33.3 KB -> 4 blocks/CU, 16 waves/CU),
//     one barrier per k-chunk, global->reg prefetch hidden under compute.
//   - GEMM inner loop in float2 packed fp32 (v_pk_fma_f32), numerically
//     identical to scalar fp32.
// B=1024, IN=512, D=256, P=8, T=32. Output [1024,256] fp32.

typedef float v2f __attribute__((ext_vector_type(2)));

constexpr int IN_DIM  = 512;
constexpr int D_DIM   = 256;
constexpr int NTOT    = 2048;   // D*P
constexpr int T_STEPS = 32;

constexpr int TM = 64;   // b-rows per block
constexpr int TN = 64;   // I-cols per block (= 8 d-groups)
constexpr int TK = 32;   // k-chunk (double-buffered)
constexpr int NCH = IN_DIM / TK;  // 16 chunks

__global__ __launch_bounds__(256, 4)
void popcode_fused(const float* __restrict__ x,
                   const float* __restrict__ Wp,
                   const float* __restrict__ bp,
                   const float* __restrict__ thrs,
                   const float* __restrict__ rateW,
                   const float* __restrict__ rateB,
                   const float* __restrict__ c1w,
                   const float* __restrict__ c1b,
                   const float* __restrict__ c2w,
                   const float* __restrict__ c2b,
                   const float* __restrict__ fus,
                   float* __restrict__ out)
{
    // As transposed [buf][k][b] stride 66: float2 reads at bank 2k+2bg,
    // conflict-free. Bs [buf][k][col] stride 64: float4 reads 2-way (free).
    __shared__ float As[2][TK][TM + 2];
    __shared__ float Bs[2][TK][TN];

    const int tid = threadIdx.x;
    const int b0  = blockIdx.x * TM;
    const int c0  = blockIdx.y * TN;
    const int bg  = tid >> 3;      // 0..31
    const int dl  = tid & 7;       // 0..7  (d-group within tile)
    const int bl0 = bg * 2;        // this thread's two b-rows

    v2f acc2[2][4];
#pragma unroll
    for (int i = 0; i < 2; ++i)
#pragma unroll
        for (int j = 0; j < 4; ++j) acc2[i][j] = v2f{0.f, 0.f};

    float4 ra[2], rb[2];

    auto load_regs = [&](int kc) {
#pragma unroll
        for (int i = 0; i < 2; ++i) {
            const int f = tid + 256 * i;
            ra[i] = *reinterpret_cast<const float4*>(
                x + (b0 + (f >> 3)) * IN_DIM + kc + (f & 7) * 4);
            rb[i] = *reinterpret_cast<const float4*>(
                Wp + (kc + (f >> 4)) * NTOT + c0 + (f & 15) * 4);
        }
    };
    auto write_lds = [&](int buf) {
#pragma unroll
        for (int i = 0; i < 2; ++i) {
            const int f   = tid + 256 * i;
            const int row = f >> 3;
            const int c4  = (f & 7) * 4;
            As[buf][c4 + 0][row] = ra[i].x;
            As[buf][c4 + 1][row] = ra[i].y;
            As[buf][c4 + 2][row] = ra[i].z;
            As[buf][c4 + 3][row] = ra[i].w;
            const int r  = f >> 4;
            const int cc = (f & 15) * 4;
            *reinterpret_cast<float4*>(&Bs[buf][r][cc]) = rb[i];
        }
    };

    // ---------------- GEMM: I = x @ W_proj (double-buffered) --------------
    load_regs(0);
    write_lds(0);
    __syncthreads();

    for (int ch = 0; ch < NCH; ++ch) {
        const int cur = ch & 1;
        if (ch + 1 < NCH) load_regs((ch + 1) * TK);

#pragma unroll
        for (int k = 0; k < TK; ++k) {
            const float2 a =
                *reinterpret_cast<const float2*>(&As[cur][k][bl0]);
            const float4 u =
                *reinterpret_cast<const float4*>(&Bs[cur][k][dl * 8]);
            const float4 v =
                *reinterpret_cast<const float4*>(&Bs[cur][k][dl * 8 + 4]);
            const v2f ax = {a.x, a.x};
            const v2f ay = {a.y, a.y};
            const v2f u0 = {u.x, u.y}, u1 = {u.z, u.w};
            const v2f v0 = {v.x, v.y}, v1 = {v.z, v.w};
            acc2[0][0] = __builtin_elementwise_fma(ax, u0, acc2[0][0]);
            acc2[0][1] = __builtin_elementwise_fma(ax, u1, acc2[0][1]);
            acc2[0][2] = __builtin_elementwise_fma(ax, v0, acc2[0][2]);
            acc2[0][3] = __builtin_elementwise_fma(ax, v1, acc2[0][3]);
            acc2[1][0] = __builtin_elementwise_fma(ay, u0, acc2[1][0]);
            acc2[1][1] = __builtin_elementwise_fma(ay, u1, acc2[1][1]);
            acc2[1][2] = __builtin_elementwise_fma(ay, v0, acc2[1][2]);
            acc2[1][3] = __builtin_elementwise_fma(ay, v1, acc2[1][3]);
        }

        if (ch + 1 < NCH) {
            write_lds(cur ^ 1);   // implicit vmcnt wait sits after compute
            __syncthreads();      // single barrier per chunk
        }
    }

    // ---------------- uniform parameters (scalar/SGPR loads) --------------
    float thr[8], rw[8];
#pragma unroll
    for (int p = 0; p < 8; ++p) { thr[p] = thrs[p]; rw[p] = rateW[p]; }

    float w1[4][8][3], wb1[4], w2c[4];
#pragma unroll
    for (int c = 0; c < 4; ++c) {
        wb1[c] = c1b[c];
        w2c[c] = c2w[c];
#pragma unroll
        for (int p = 0; p < 8; ++p)
#pragma unroll
            for (int k = 0; k < 3; ++k)
                w1[c][p][k] = c1w[(c * 8 + p) * 3 + k];
    }
    const float rb_  = rateB[0];
    const float bb2 = c2b[0];
    const float f0 = fus[0], f1 = fus[1];
    const float fm = fmaxf(f0, f1);
    const float e0 = __expf(f0 - fm), e1 = __expf(f1 - fm);
    const float inv = 1.f / (e0 + e1);
    const float fw0 = e0 * inv, fw1 = e1 * inv;

    float bpv[8];
#pragma unroll
    for (int p = 0; p < 8; ++p) bpv[p] = bp[c0 + dl * 8 + p];

    // ---------------- per-(b,d): LIF -> rate + conv -> output -------------
#pragma unroll
    for (int bi = 0; bi < 2; ++bi) {
        float Iv[8], Imt[8], mem[8];
        unsigned swv[8];
        bool spk[8];
#pragma unroll
        for (int p = 0; p < 8; ++p) {
            const float a = (p & 1) ? acc2[bi][p >> 1].y : acc2[bi][p >> 1].x;
            Iv[p]  = a + bpv[p];
            Imt[p] = Iv[p] - thr[p];   // I - thr (used when reset fires)
            mem[p] = 0.f;
            swv[p] = 0u;
            spk[p] = false;
        }

        // LIF: reset_t = spk_{t-1}; mem = beta*mem + I - reset*thr; spk = mem>thr
        for (int t = 0; t < T_STEPS; ++t) {
            const unsigned bit = 1u << t;
#pragma unroll
            for (int p = 0; p < 8; ++p) {
                mem[p] = 0.95f * mem[p] + (spk[p] ? Imt[p] : Iv[p]);
                spk[p] = mem[p] > thr[p];
                swv[p] |= spk[p] ? bit : 0u;
            }
        }

        // rate branch: popcount/32 dot rate_W
        float rsum = 0.f;
#pragma unroll
        for (int p = 0; p < 8; ++p) rsum += (float)__popc(swv[p]) * rw[p];
        const float rdec = rsum * (1.f / 32.f) + rb_;

        // temporal branch: conv1(P->4,K=3,SAME) -> relu -> conv2(4->1,K=1) -> mean_t
        float svp[8], svc[8], svn[8];
#pragma unroll
        for (int p = 0; p < 8; ++p) {
            svp[p] = 0.f;
            svc[p] = (float)(swv[p] & 1u);
        }
        float tacc = 0.f;
#pragma unroll 4
        for (int t = 0; t < T_STEPS; ++t) {
#pragma unroll
            for (int p = 0; p < 8; ++p)
                svn[p] = (t < 31) ? (float)((swv[p] >> (t + 1)) & 1u) : 0.f;
#pragma unroll
            for (int c = 0; c < 4; ++c) {
                float h = wb1[c];
#pragma unroll
                for (int p = 0; p < 8; ++p) {
                    h = fmaf(w1[c][p][0], svp[p], h);
                    h = fmaf(w1[c][p][1], svc[p], h);
                    h = fmaf(w1[c][p][2], svn[p], h);
                }
                tacc = fmaf(fmaxf(h, 0.f), w2c[c], tacc);
            }
#pragma unroll
            for (int p = 0; p < 8; ++p) { svp[p] = svc[p]; svc[p] = svn[p]; }
        }
        const float temp = tacc * (1.f / 32.f) + bb2;

        out[(b0 + bl0 + bi) * D_DIM + (c0 >> 3) + dl] = fw0 * rdec + fw1 * temp;
    }
}

extern "C" void kernel_launch(void* const* d_in, const int* in_sizes, int n_in,
                              void* d_out, int out_size, void* d_ws, size_t ws_size,
                              hipStream_t stream) {
    const float* x     = (const float*)d_in[0];
    const float* Wp    = (const float*)d_in[1];
    const float* bp    = (const float*)d_in[2];
    const float* thrs  = (const float*)d_in[3];
    const float* rateW = (const float*)d_in[4];
    const float* rateB = (const float*)d_in[5];
    const float* c1w   = (const float*)d_in[6];
    const float* c1b   = (const float*)d_in[7];
    const float* c2w   = (const float*)d_in[8];
    const float* c2b   = (const float*)d_in[9];
    const float* fus   = (const float*)d_in[10];
    float* out = (float*)d_out;

    dim3 grid(1024 / TM, 2048 / TN);   // 16 x 32 = 512 blocks
    popcode_fused<<<grid, dim3(256), 0, stream>>>(
        x, Wp, bp, thrs, rateW, rateB, c1w, c1b, c2w, c2b, fus, out);
}

// Round 3
// 156.832 us; speedup vs baseline: 1.3312x; 1.3312x over previous
//
#include <hip/hip_runtime.h>

// PopulationCoding fused kernel, round 3:
//   - 512-thread blocks on a 64x64 tile (1 b-row x 8 cols per thread):
//     2 blocks/CU x 8 waves = 16 waves/CU (2x round-1 occupancy), same
//     single-buffered LDS structure that ran spill-free at 52 VGPR.
//   - As stored [row][k] (+4 pad): staging = ds_write_b128, inner read is
//     8-address broadcast, conflict-free.
// B=1024, IN=512, D=256, P=8, T=32. Output [1024,256] fp32.

constexpr int IN_DIM  = 512;
constexpr int D_DIM   = 256;
constexpr int NTOT    = 2048;   // D*P
constexpr int T_STEPS = 32;

constexpr int TM = 64;   // b-rows per block
constexpr int TN = 64;   // I-cols per block (= 8 d-groups)
constexpr int TK = 64;   // k-chunk

__global__ __launch_bounds__(512, 4)
void popcode_fused(const float* __restrict__ x,
                   const float* __restrict__ Wp,
                   const float* __restrict__ bp,
                   const float* __restrict__ thrs,
                   const float* __restrict__ rateW,
                   const float* __restrict__ rateB,
                   const float* __restrict__ c1w,
                   const float* __restrict__ c1b,
                   const float* __restrict__ c2w,
                   const float* __restrict__ c2b,
                   const float* __restrict__ fus,
                   float* __restrict__ out)
{
    // As [row][k] stride 68: inner read As[bg][k] -> 8 unique addrs/wave,
    // banks (4*bg + k)%32 distinct, 8-way broadcast, conflict-free.
    // Bs [k][col] stride 64: float4 reads 2-way bank-aliased (free).
    __shared__ float As[TM][TK + 4];
    __shared__ float Bs[TK][TN];

    const int tid = threadIdx.x;           // 0..511
    const int b0  = blockIdx.x * TM;
    const int c0  = blockIdx.y * TN;
    const int bg  = tid >> 3;              // 0..63  (this thread's b-row)
    const int dl  = tid & 7;               // 0..7   (d-group within tile)

    float acc[8];
#pragma unroll
    for (int j = 0; j < 8; ++j) acc[j] = 0.f;

    // ---------------- GEMM: I = x @ W_proj ----------------
    for (int kc = 0; kc < IN_DIM; kc += TK) {
        // stage A: 64x64 floats, 512 threads x 2 float4, row-major b128 writes
#pragma unroll
        for (int i = 0; i < 2; ++i) {
            const int f   = tid + 512 * i;       // 0..1023
            const int row = f >> 4;              // 0..63
            const int c4  = (f & 15) * 4;        // 0..60
            *reinterpret_cast<float4*>(&As[row][c4]) =
                *reinterpret_cast<const float4*>(x + (b0 + row) * IN_DIM + kc + c4);
        }
        // stage B
#pragma unroll
        for (int i = 0; i < 2; ++i) {
            const int f  = tid + 512 * i;
            const int r  = f >> 4;
            const int c4 = (f & 15) * 4;
            *reinterpret_cast<float4*>(&Bs[r][c4]) =
                *reinterpret_cast<const float4*>(Wp + (kc + r) * NTOT + c0 + c4);
        }
        __syncthreads();

#pragma unroll 16
        for (int k = 0; k < TK; ++k) {
            const float a = As[bg][k];
            const float4 u = *reinterpret_cast<const float4*>(&Bs[k][dl * 8]);
            const float4 v = *reinterpret_cast<const float4*>(&Bs[k][dl * 8 + 4]);
            acc[0] += a * u.x;  acc[1] += a * u.y;
            acc[2] += a * u.z;  acc[3] += a * u.w;
            acc[4] += a * v.x;  acc[5] += a * v.y;
            acc[6] += a * v.z;  acc[7] += a * v.w;
        }
        __syncthreads();
    }

    // ---------------- uniform parameters (scalar/SGPR loads) --------------
    float thr[8], rw[8];
#pragma unroll
    for (int p = 0; p < 8; ++p) { thr[p] = thrs[p]; rw[p] = rateW[p]; }

    float w1[4][8][3], wb1[4], w2c[4];
#pragma unroll
    for (int c = 0; c < 4; ++c) {
        wb1[c] = c1b[c];
        w2c[c] = c2w[c];
#pragma unroll
        for (int p = 0; p < 8; ++p)
#pragma unroll
            for (int k = 0; k < 3; ++k)
                w1[c][p][k] = c1w[(c * 8 + p) * 3 + k];
    }
    const float rb_ = rateB[0];
    const float bb2 = c2b[0];
    const float f0 = fus[0], f1 = fus[1];
    const float fm = fmaxf(f0, f1);
    const float e0 = __expf(f0 - fm), e1 = __expf(f1 - fm);
    const float inv = 1.f / (e0 + e1);
    const float fw0 = e0 * inv, fw1 = e1 * inv;

    // ---------------- per-(b,d): LIF -> rate + conv -> output -------------
    float Iv[8], Imt[8], mem[8];
    unsigned swv[8];
    bool spk[8];
#pragma unroll
    for (int p = 0; p < 8; ++p) {
        Iv[p]  = acc[p] + bp[c0 + dl * 8 + p];
        Imt[p] = Iv[p] - thr[p];   // I - thr (used when reset fires)
        mem[p] = 0.f;
        swv[p] = 0u;
        spk[p] = false;
    }

    // LIF: reset_t = spk_{t-1}; mem = beta*mem + I - reset*thr; spk = mem>thr
    for (int t = 0; t < T_STEPS; ++t) {
        const unsigned bit = 1u << t;
#pragma unroll
        for (int p = 0; p < 8; ++p) {
            mem[p] = 0.95f * mem[p] + (spk[p] ? Imt[p] : Iv[p]);
            spk[p] = mem[p] > thr[p];
            swv[p] |= spk[p] ? bit : 0u;
        }
    }

    // rate branch: popcount/32 dot rate_W
    float rsum = 0.f;
#pragma unroll
    for (int p = 0; p < 8; ++p) rsum += (float)__popc(swv[p]) * rw[p];
    const float rdec = rsum * (1.f / 32.f) + rb_;

    // temporal branch: conv1(P->4,K=3,SAME) -> relu -> conv2(4->1,K=1) -> mean_t
    float svp[8], svc[8], svn[8];
#pragma unroll
    for (int p = 0; p < 8; ++p) {
        svp[p] = 0.f;
        svc[p] = (float)(swv[p] & 1u);
    }
    float tacc = 0.f;
#pragma unroll 4
    for (int t = 0; t < T_STEPS; ++t) {
#pragma unroll
        for (int p = 0; p < 8; ++p)
            svn[p] = (t < 31) ? (float)((swv[p] >> (t + 1)) & 1u) : 0.f;
#pragma unroll
        for (int c = 0; c < 4; ++c) {
            float h = wb1[c];
#pragma unroll
            for (int p = 0; p < 8; ++p) {
                h = fmaf(w1[c][p][0], svp[p], h);
                h = fmaf(w1[c][p][1], svc[p], h);
                h = fmaf(w1[c][p][2], svn[p], h);
            }
            tacc = fmaf(fmaxf(h, 0.f), w2c[c], tacc);
        }
#pragma unroll
        for (int p = 0; p < 8; ++p) { svp[p] = svc[p]; svc[p] = svn[p]; }
    }
    const float temp = tacc * (1.f / 32.f) + bb2;

    out[(b0 + bg) * D_DIM + (c0 >> 3) + dl] = fw0 * rdec + fw1 * temp;
}

extern "C" void kernel_launch(void* const* d_in, const int* in_sizes, int n_in,
                              void* d_out, int out_size, void* d_ws, size_t ws_size,
                              hipStream_t stream) {
    const float* x     = (const float*)d_in[0];
    const float* Wp    = (const float*)d_in[1];
    const float* bp    = (const float*)d_in[2];
    const float* thrs  = (const float*)d_in[3];
    const float* rateW = (const float*)d_in[4];
    const float* rateB = (const float*)d_in[5];
    const float* c1w   = (const float*)d_in[6];
    const float* c1b   = (const float*)d_in[7];
    const float* c2w   = (const float*)d_in[8];
    const float* c2b   = (const float*)d_in[9];
    const float* fus   = (const float*)d_in[10];
    float* out = (float*)d_out;

    dim3 grid(1024 / TM, 2048 / TN);   // 16 x 32 = 512 blocks
    popcode_fused<<<grid, dim3(512), 0, stream>>>(
        x, Wp, bp, thrs, rateW, rateB, c1w, c1b, c2w, c2b, fus, out);
}